// Round 7
// baseline (224.481 us; speedup 1.0000x reference)
//
#include <hip/hip_runtime.h>

#define IN_F 4096
#define OUT_F 4096
#define NTOK 8192   // B*S = 4*2048
#define KDIM 4096

using i32x4 = __attribute__((ext_vector_type(4))) int;
using f32x4 = __attribute__((ext_vector_type(4))) float;

__device__ __forceinline__ void gload_lds16(const void* g, void* l) {
  __builtin_amdgcn_global_load_lds(
      (const __attribute__((address_space(1))) void*)g,
      (__attribute__((address_space(3))) void*)l, 16, 0, 0);
}

#define WAITV(n) asm volatile("s_waitcnt vmcnt(" #n ")" ::: "memory")
#define BAR() do { asm volatile("" ::: "memory"); __builtin_amdgcn_s_barrier(); \
                   asm volatile("" ::: "memory"); } while (0)

// ---------------- Pass 1: RMSNorm + per-token int8 absmax quant ------------
__global__ __launch_bounds__(256) void rmsq_kernel(
    const float* __restrict__ x, const float* __restrict__ rmsw,
    signed char* __restrict__ q, float* __restrict__ dscale) {
  const int tok = blockIdx.x;
  const int tid = threadIdx.x;
  const f32x4* xr = (const f32x4*)(x + (size_t)tok * IN_F);
  const f32x4* wr = (const f32x4*)rmsw;

  f32x4 v[4];
  float ss = 0.f;
#pragma unroll
  for (int c = 0; c < 4; ++c) {
    v[c] = xr[c * 256 + tid];
    ss += v[c].x * v[c].x + v[c].y * v[c].y + v[c].z * v[c].z + v[c].w * v[c].w;
  }

  __shared__ float red[4];
#pragma unroll
  for (int off = 32; off > 0; off >>= 1) ss += __shfl_down(ss, off, 64);
  const int wid = tid >> 6;
  if ((tid & 63) == 0) red[wid] = ss;
  __syncthreads();
  const float tot = red[0] + red[1] + red[2] + red[3];
  const float rinv = rsqrtf(tot * (1.0f / IN_F) + 1e-6f);

  f32x4 h[4];
  float amax = 0.f;
#pragma unroll
  for (int c = 0; c < 4; ++c) {
    f32x4 w = wr[c * 256 + tid];
    h[c].x = v[c].x * rinv * w.x;
    h[c].y = v[c].y * rinv * w.y;
    h[c].z = v[c].z * rinv * w.z;
    h[c].w = v[c].w * rinv * w.w;
    amax = fmaxf(amax, fabsf(h[c].x));
    amax = fmaxf(amax, fabsf(h[c].y));
    amax = fmaxf(amax, fabsf(h[c].z));
    amax = fmaxf(amax, fabsf(h[c].w));
  }

  __syncthreads();
#pragma unroll
  for (int off = 32; off > 0; off >>= 1)
    amax = fmaxf(amax, __shfl_down(amax, off, 64));
  if ((tid & 63) == 0) red[wid] = amax;
  __syncthreads();
  amax = fmaxf(fmaxf(red[0], red[1]), fmaxf(red[2], red[3]));
  amax = fmaxf(amax, 1e-5f);
  const float qs = 127.0f / amax;
  if (tid == 0) dscale[tok] = amax * (1.0f / 127.0f);

  uint* qo = (uint*)(q + (size_t)tok * IN_F);
#pragma unroll
  for (int c = 0; c < 4; ++c) {
    float r0 = fminf(fmaxf(rintf(h[c].x * qs), -128.f), 127.f);
    float r1 = fminf(fmaxf(rintf(h[c].y * qs), -128.f), 127.f);
    float r2 = fminf(fmaxf(rintf(h[c].z * qs), -128.f), 127.f);
    float r3 = fminf(fmaxf(rintf(h[c].w * qs), -128.f), 127.f);
    uint p = ((uint)((int)r0 & 255)) | ((uint)((int)r1 & 255) << 8) |
             ((uint)((int)r2 & 255) << 16) | ((uint)((int)r3 & 255) << 24);
    qo[c * 256 + tid] = p;
  }
}

// ---------------- Pass 2: W float32 {-1,0,1} -> int8 ----------------------
__global__ __launch_bounds__(256) void wconv_kernel(
    const float* __restrict__ W, signed char* __restrict__ Wq) {
  const int idx = blockIdx.x * 256 + threadIdx.x;
  f32x4 w = ((const f32x4*)W)[idx];
  uint p = ((uint)((int)w.x & 255)) | ((uint)((int)w.y & 255) << 8) |
           ((uint)((int)w.z & 255) << 16) | ((uint)((int)w.w & 255) << 24);
  ((uint*)Wq)[idx] = p;
}

// ---------------- Pass 3: int8 GEMM, A via LDS, B direct from L2 -----------
// 128x256 tile, BK=64, 4 waves (wave = 128x64 out). A staged via
// global_load_lds (shared 4x across waves), depth-3, 4 buffers (32 KB LDS ->
// 2 blocks/CU). B fragments: global->register, double-buffered 1 tile ahead
// (B has NO cross-wave sharing; each XCD's B-panel is 2 MB = L2-resident).
// LDS traffic/block-tile: 72 KB -> 40 KB; MFMA becomes the critical pipe.
#define BM 128
#define BN 256
#define BK 64
#define NT (KDIM / BK)       // 64 K-tiles
#define ATILEB (BM * BK)     // 8192 B per A buffer
#define NBUF 4

__global__ __launch_bounds__(256, 2) void gemm_kernel(
    const signed char* __restrict__ A, const signed char* __restrict__ Bw,
    const float* __restrict__ dscale, const float* __restrict__ bias,
    const float* __restrict__ wscale_p, float* __restrict__ out) {
  __shared__ __align__(16) signed char lds[NBUF * ATILEB];  // 32 KB

  const int tid = threadIdx.x;
  const int lane = tid & 63;
  const int wc = tid >> 6;   // 0..3 : 64 output cols each

  // XCD-aware bijective swizzle (1024 blocks, 1024%8==0); consecutive swz on
  // one XCD share the B-panel (n0) -> W stays L2-resident per XCD.
  const int bid = blockIdx.x;
  const int swz = (bid & 7) * 128 + (bid >> 3);
  const int m0 = (swz & 63) * BM;
  const int n0 = (swz >> 6) * BN;

  // A staging: chunk c -> row r=c>>2, phys slot p=c&3 holds logical slot
  // s = p ^ ((r>>1)&3)  (pre-swizzled global source, linear LDS dest)
  const int cA0 = tid, cA1 = tid + 256;          // 512 chunks
  const int rA0 = cA0 >> 2, rA1 = cA1 >> 2;
  const int sA0 = (cA0 & 3) ^ ((rA0 >> 1) & 3);
  const int sA1 = (cA1 & 3) ^ ((rA1 >> 1) & 3);
  const signed char* agp0 = A + (size_t)(m0 + rA0) * KDIM + sA0 * 16;
  const signed char* agp1 = A + (size_t)(m0 + rA1) * KDIM + sA1 * 16;

#define STAGE_A(kt, boff)                                                  \
  do {                                                                     \
    const int k0_ = (kt) * BK;                                             \
    signed char* lb_ = &lds[(boff)];                                       \
    gload_lds16(agp0 + k0_, lb_ + cA0 * 16);                               \
    gload_lds16(agp1 + k0_, lb_ + cA1 * 16);                               \
  } while (0)

  // A fragment read offsets (swizzled, loop-invariant)
  const int fr = lane & 15;
  const int ks = lane >> 4;
  int offA[8];
#pragma unroll
  for (int mi = 0; mi < 8; ++mi) {
    const int row = mi * 16 + fr;
    offA[mi] = row * BK + ((ks ^ ((row >> 1) & 3)) * 16);
  }

  // B fragment global pointers (L2-resident panel)
  const signed char* bgl[4];
#pragma unroll
  for (int ni = 0; ni < 4; ++ni)
    bgl[ni] = Bw + (size_t)(n0 + wc * 64 + ni * 16 + fr) * KDIM + ks * 16;

  i32x4 acc[8][4];
#pragma unroll
  for (int i = 0; i < 8; ++i)
#pragma unroll
    for (int j = 0; j < 4; ++j) acc[i][j] = (i32x4){0, 0, 0, 0};

  // prologue: A depth-3, B tile-0 into regs
  STAGE_A(0, 0);
  STAGE_A(1, ATILEB);
  STAGE_A(2, 2 * ATILEB);
  i32x4 bcur0 = *(const i32x4*)(bgl[0]);
  i32x4 bcur1 = *(const i32x4*)(bgl[1]);
  i32x4 bcur2 = *(const i32x4*)(bgl[2]);
  i32x4 bcur3 = *(const i32x4*)(bgl[3]);

  int br = 0;              // buffer holding A tile t
  int bs = 3 * ATILEB;     // buffer to stage A tile t+3 into
  for (int t = 0; t < NT; ++t) {
    // own A(t) chunks done: <=8 ops issued after A(t)'s (exact at t=0 and
    // tails; steady-state no-op thanks to compiler's B-register waits)
    WAITV(8);
    BAR();

    const signed char* bp = &lds[br];
    i32x4 af[8];
#pragma unroll
    for (int mi = 0; mi < 8; ++mi) af[mi] = *(const i32x4*)(bp + offA[mi]);

    // B prefetch for tile t+1 (registers; compiler-managed waits)
    i32x4 bn0, bn1, bn2, bn3;
    if (t + 1 < NT) {
      const int ko = (t + 1) * BK;
      bn0 = *(const i32x4*)(bgl[0] + ko);
      bn1 = *(const i32x4*)(bgl[1] + ko);
      bn2 = *(const i32x4*)(bgl[2] + ko);
      bn3 = *(const i32x4*)(bgl[3] + ko);
    }

    // stage A tile t+3
    if (t + 3 < NT) STAGE_A(t + 3, bs);

    __builtin_amdgcn_s_setprio(1);
#pragma unroll
    for (int mi = 0; mi < 8; ++mi) {
      acc[mi][0] = __builtin_amdgcn_mfma_i32_16x16x64_i8(af[mi], bcur0, acc[mi][0], 0, 0, 0);
      acc[mi][1] = __builtin_amdgcn_mfma_i32_16x16x64_i8(af[mi], bcur1, acc[mi][1], 0, 0, 0);
      acc[mi][2] = __builtin_amdgcn_mfma_i32_16x16x64_i8(af[mi], bcur2, acc[mi][2], 0, 0, 0);
      acc[mi][3] = __builtin_amdgcn_mfma_i32_16x16x64_i8(af[mi], bcur3, acc[mi][3], 0, 0, 0);
    }
    __builtin_amdgcn_s_setprio(0);

    bcur0 = bn0; bcur1 = bn1; bcur2 = bn2; bcur3 = bn3;
    br += ATILEB; if (br == NBUF * ATILEB) br = 0;
    bs += ATILEB; if (bs == NBUF * ATILEB) bs = 0;
  }

  // epilogue: dequant + bias + weight_scale
  const float wsc = wscale_p[0];
  const int rbase = (lane >> 4) * 4;
  float bv[4];
#pragma unroll
  for (int ni = 0; ni < 4; ++ni) bv[ni] = bias[n0 + wc * 64 + ni * 16 + fr];
#pragma unroll
  for (int mi = 0; mi < 8; ++mi) {
#pragma unroll
    for (int r = 0; r < 4; ++r) {
      const int m = m0 + mi * 16 + rbase + r;
      const float ds = dscale[m];
      float* orow = out + (size_t)m * OUT_F + n0 + wc * 64;
#pragma unroll
      for (int ni = 0; ni < 4; ++ni) {
        orow[ni * 16 + fr] = ((float)acc[mi][ni][r] * ds + bv[ni]) * wsc;
      }
    }
  }
#undef STAGE_A
}

extern "C" void kernel_launch(void* const* d_in, const int* in_sizes, int n_in,
                              void* d_out, int out_size, void* d_ws, size_t ws_size,
                              hipStream_t stream) {
  const float* x = (const float*)d_in[0];
  const float* W = (const float*)d_in[1];
  const float* rmsw = (const float*)d_in[2];
  const float* bias = (const float*)d_in[3];
  const float* wscale = (const float*)d_in[4];
  float* out = (float*)d_out;

  signed char* q = (signed char*)d_ws;                     // 32 MB
  signed char* Wq = q + (size_t)NTOK * IN_F;               // 16 MB
  float* dscale = (float*)(Wq + (size_t)OUT_F * IN_F);     // 32 KB

  rmsq_kernel<<<NTOK, 256, 0, stream>>>(x, rmsw, q, dscale);
  wconv_kernel<<<(OUT_F * IN_F / 4) / 256, 256, 0, stream>>>(W, Wq);
  gemm_kernel<<<(NTOK / BM) * (OUT_F / BN), 256, 0, stream>>>(q, Wq, dscale,
                                                              bias, wscale, out);
}

// Round 8
// 189.863 us; speedup vs baseline: 1.1823x; 1.1823x over previous
//
#include <hip/hip_runtime.h>

#define IN_F 4096
#define OUT_F 4096
#define NTOK 8192   // B*S = 4*2048
#define KDIM 4096

using i32x4 = __attribute__((ext_vector_type(4))) int;
using f32x4 = __attribute__((ext_vector_type(4))) float;

__device__ __forceinline__ void gload_lds16(const void* g, void* l) {
  __builtin_amdgcn_global_load_lds(
      (const __attribute__((address_space(1))) void*)g,
      (__attribute__((address_space(3))) void*)l, 16, 0, 0);
}

#define WAITV(n) asm volatile("s_waitcnt vmcnt(" #n ")" ::: "memory")
#define BAR() do { asm volatile("" ::: "memory"); __builtin_amdgcn_s_barrier(); \
                   asm volatile("" ::: "memory"); } while (0)

// ---------------- Pass 1: RMSNorm + per-token int8 absmax quant ------------
__global__ __launch_bounds__(256) void rmsq_kernel(
    const float* __restrict__ x, const float* __restrict__ rmsw,
    signed char* __restrict__ q, float* __restrict__ dscale) {
  const int tok = blockIdx.x;
  const int tid = threadIdx.x;
  const f32x4* xr = (const f32x4*)(x + (size_t)tok * IN_F);
  const f32x4* wr = (const f32x4*)rmsw;

  f32x4 v[4];
  float ss = 0.f;
#pragma unroll
  for (int c = 0; c < 4; ++c) {
    v[c] = xr[c * 256 + tid];
    ss += v[c].x * v[c].x + v[c].y * v[c].y + v[c].z * v[c].z + v[c].w * v[c].w;
  }

  __shared__ float red[4];
#pragma unroll
  for (int off = 32; off > 0; off >>= 1) ss += __shfl_down(ss, off, 64);
  const int wid = tid >> 6;
  if ((tid & 63) == 0) red[wid] = ss;
  __syncthreads();
  const float tot = red[0] + red[1] + red[2] + red[3];
  const float rinv = rsqrtf(tot * (1.0f / IN_F) + 1e-6f);

  f32x4 h[4];
  float amax = 0.f;
#pragma unroll
  for (int c = 0; c < 4; ++c) {
    f32x4 w = wr[c * 256 + tid];
    h[c].x = v[c].x * rinv * w.x;
    h[c].y = v[c].y * rinv * w.y;
    h[c].z = v[c].z * rinv * w.z;
    h[c].w = v[c].w * rinv * w.w;
    amax = fmaxf(amax, fabsf(h[c].x));
    amax = fmaxf(amax, fabsf(h[c].y));
    amax = fmaxf(amax, fabsf(h[c].z));
    amax = fmaxf(amax, fabsf(h[c].w));
  }

  __syncthreads();
#pragma unroll
  for (int off = 32; off > 0; off >>= 1)
    amax = fmaxf(amax, __shfl_down(amax, off, 64));
  if ((tid & 63) == 0) red[wid] = amax;
  __syncthreads();
  amax = fmaxf(fmaxf(red[0], red[1]), fmaxf(red[2], red[3]));
  amax = fmaxf(amax, 1e-5f);
  const float qs = 127.0f / amax;
  if (tid == 0) dscale[tok] = amax * (1.0f / 127.0f);

  uint* qo = (uint*)(q + (size_t)tok * IN_F);
#pragma unroll
  for (int c = 0; c < 4; ++c) {
    float r0 = fminf(fmaxf(rintf(h[c].x * qs), -128.f), 127.f);
    float r1 = fminf(fmaxf(rintf(h[c].y * qs), -128.f), 127.f);
    float r2 = fminf(fmaxf(rintf(h[c].z * qs), -128.f), 127.f);
    float r3 = fminf(fmaxf(rintf(h[c].w * qs), -128.f), 127.f);
    uint p = ((uint)((int)r0 & 255)) | ((uint)((int)r1 & 255) << 8) |
             ((uint)((int)r2 & 255) << 16) | ((uint)((int)r3 & 255) << 24);
    qo[c * 256 + tid] = p;
  }
}

// ---------------- Pass 2: W float32 {-1,0,1} -> int8 ----------------------
__global__ __launch_bounds__(256) void wconv_kernel(
    const float* __restrict__ W, signed char* __restrict__ Wq) {
  const int idx = blockIdx.x * 256 + threadIdx.x;
  f32x4 w = ((const f32x4*)W)[idx];
  uint p = ((uint)((int)w.x & 255)) | ((uint)((int)w.y & 255) << 8) |
           ((uint)((int)w.z & 255) << 16) | ((uint)((int)w.w & 255) << 24);
  ((uint*)Wq)[idx] = p;
}

// ---------------- Pass 3: int8 GEMM, 2 blocks/CU, m-stripe per XCD ---------
// 128x256 tile, BK=64, 4 waves (wave = 128x64 out). 3 LDS buffers (24 KB
// each, 72 KB -> 2 blocks/CU). Depth-2 prefetch, counted vmcnt(6), ONE
// barrier per tile. XCD mapping: XCD x owns m-blocks [x*8, x*8+8), sweeps n
// fastest -> per-XCD A working set = 4 MB (L2-resident, fetched ONCE);
// Wq (16 MB chip-wide) stays L3-resident. Cuts q re-fetch from HBM.
#define BM 128
#define BN 256
#define BK 64
#define NT (KDIM / BK)       // 64 K-tiles
#define ATILEB (BM * BK)     // 8192
#define BTILEB (BN * BK)     // 16384
#define BUFB (ATILEB + BTILEB)  // 24576
#define NBUF 3

__global__ __launch_bounds__(256, 2) void gemm_kernel(
    const signed char* __restrict__ A, const signed char* __restrict__ Bw,
    const float* __restrict__ dscale, const float* __restrict__ bias,
    const float* __restrict__ wscale_p, float* __restrict__ out) {
  __shared__ __align__(16) signed char lds[NBUF * BUFB];  // 72 KB

  const int tid = threadIdx.x;
  const int lane = tid & 63;
  const int wc = tid >> 6;   // 0..3 : 64 output cols each

  // m-stripe-per-XCD mapping (1024 blocks = 64 m x 16 n; bid&7 = XCD):
  // XCD x owns m_local 0..7 -> m-block = x*8 + (j>>4); n-block = j&15
  // (n fastest). Per-XCD A stripe = 8*128 rows = 4 MB -> L2-resident once.
  const int bid = blockIdx.x;
  const int x = bid & 7;
  const int j = bid >> 3;           // 0..127
  const int m0 = (x * 8 + (j >> 4)) * BM;
  const int n0 = (j & 15) * BN;

  // staging: chunk c -> row r=c>>2, phys slot p=c&3 holds logical slot
  // s = p ^ ((r>>1)&3)  (pre-swizzled global source, linear LDS dest)
  const int cA0 = tid, cA1 = tid + 256;          // A: 512 chunks
  const int rA0 = cA0 >> 2, rA1 = cA1 >> 2;
  const int sA0 = (cA0 & 3) ^ ((rA0 >> 1) & 3);
  const int sA1 = (cA1 & 3) ^ ((rA1 >> 1) & 3);
  const signed char* agp0 = A + (size_t)(m0 + rA0) * KDIM + sA0 * 16;
  const signed char* agp1 = A + (size_t)(m0 + rA1) * KDIM + sA1 * 16;
  // B: 1024 chunks, rows 0..255
  const int rB = tid >> 2;
  const signed char* bgp[4];
#pragma unroll
  for (int jj = 0; jj < 4; ++jj) {
    const int rBj = rB + jj * 64;
    const int sBj = (tid & 3) ^ ((rBj >> 1) & 3);
    bgp[jj] = Bw + (size_t)(n0 + rBj) * KDIM + sBj * 16;
  }

#define STAGE(kt, boff)                                                    \
  do {                                                                     \
    const int k0_ = (kt) * BK;                                             \
    signed char* lb_ = &lds[(boff)];                                       \
    gload_lds16(agp0 + k0_, lb_ + cA0 * 16);                               \
    gload_lds16(agp1 + k0_, lb_ + cA1 * 16);                               \
    gload_lds16(bgp[0] + k0_, lb_ + ATILEB + (tid + 0 * 256) * 16);        \
    gload_lds16(bgp[1] + k0_, lb_ + ATILEB + (tid + 1 * 256) * 16);        \
    gload_lds16(bgp[2] + k0_, lb_ + ATILEB + (tid + 2 * 256) * 16);        \
    gload_lds16(bgp[3] + k0_, lb_ + ATILEB + (tid + 3 * 256) * 16);        \
  } while (0)

  // fragment read offsets (swizzled, loop-invariant)
  const int fr = lane & 15;
  const int ks = lane >> 4;
  int offA[8], offB[4];
#pragma unroll
  for (int mi = 0; mi < 8; ++mi) {
    const int row = mi * 16 + fr;
    offA[mi] = row * BK + ((ks ^ ((row >> 1) & 3)) * 16);
  }
#pragma unroll
  for (int ni = 0; ni < 4; ++ni) {
    const int row = wc * 64 + ni * 16 + fr;
    offB[ni] = ATILEB + row * BK + ((ks ^ ((row >> 1) & 3)) * 16);
  }

  i32x4 acc[8][4];
#pragma unroll
  for (int i = 0; i < 8; ++i)
#pragma unroll
    for (int jj = 0; jj < 4; ++jj) acc[i][jj] = (i32x4){0, 0, 0, 0};

  // prologue: depth-2 fill (tile-0 guard is the loop's WAITV(6))
  STAGE(0, 0);
  STAGE(1, BUFB);

  int br = 0;             // buffer holding tile t
  int bs = 2 * BUFB;      // buffer to stage tile t+2 into
  for (int t = 0; t < NT; ++t) {
    if (t < NT - 1) WAITV(6); else WAITV(0);
    BAR();

    const signed char* bp = &lds[br];
    i32x4 af[8], bf[4];
#pragma unroll
    for (int mi = 0; mi < 8; ++mi) af[mi] = *(const i32x4*)(bp + offA[mi]);
#pragma unroll
    for (int ni = 0; ni < 4; ++ni) bf[ni] = *(const i32x4*)(bp + offB[ni]);

    if (t + 2 < NT) STAGE(t + 2, bs);

    __builtin_amdgcn_s_setprio(1);
#pragma unroll
    for (int mi = 0; mi < 8; ++mi)
#pragma unroll
      for (int ni = 0; ni < 4; ++ni)
        acc[mi][ni] = __builtin_amdgcn_mfma_i32_16x16x64_i8(af[mi], bf[ni],
                                                            acc[mi][ni], 0, 0, 0);
    __builtin_amdgcn_s_setprio(0);

    br += BUFB; if (br == NBUF * BUFB) br = 0;
    bs += BUFB; if (bs == NBUF * BUFB) bs = 0;
  }

  // epilogue: dequant + bias + weight_scale
  const float wsc = wscale_p[0];
  const int rbase = (lane >> 4) * 4;
  float bv[4];
#pragma unroll
  for (int ni = 0; ni < 4; ++ni) bv[ni] = bias[n0 + wc * 64 + ni * 16 + fr];
#pragma unroll
  for (int mi = 0; mi < 8; ++mi) {
#pragma unroll
    for (int r = 0; r < 4; ++r) {
      const int m = m0 + mi * 16 + rbase + r;
      const float ds = dscale[m];
      float* orow = out + (size_t)m * OUT_F + n0 + wc * 64;
#pragma unroll
      for (int ni = 0; ni < 4; ++ni) {
        orow[ni * 16 + fr] = ((float)acc[mi][ni][r] * ds + bv[ni]) * wsc;
      }
    }
  }
#undef STAGE
}

extern "C" void kernel_launch(void* const* d_in, const int* in_sizes, int n_in,
                              void* d_out, int out_size, void* d_ws, size_t ws_size,
                              hipStream_t stream) {
  const float* x = (const float*)d_in[0];
  const float* W = (const float*)d_in[1];
  const float* rmsw = (const float*)d_in[2];
  const float* bias = (const float*)d_in[3];
  const float* wscale = (const float*)d_in[4];
  float* out = (float*)d_out;

  signed char* q = (signed char*)d_ws;                     // 32 MB
  signed char* Wq = q + (size_t)NTOK * IN_F;               // 16 MB
  float* dscale = (float*)(Wq + (size_t)OUT_F * IN_F);     // 32 KB

  rmsq_kernel<<<NTOK, 256, 0, stream>>>(x, rmsw, q, dscale);
  wconv_kernel<<<(OUT_F * IN_F / 4) / 256, 256, 0, stream>>>(W, Wq);
  gemm_kernel<<<(NTOK / BM) * (OUT_F / BN), 256, 0, stream>>>(q, Wq, dscale,
                                                              bias, wscale, out);
}